// Round 4
// baseline (342.731 us; speedup 1.0000x reference)
//
#include <hip/hip_runtime.h>
#include <math.h>

#define BB 2
#define SS 2048
#define EE 2048
#define HH 16
#define KVHH 4
#define DD 128
#define GG (HH / KVHH)
#define KVN (KVHH * DD)   // 512
#define SCALE 0.08838834764831843f
// SCALE * log2(e): scores land in log2 domain -> exp2f softmax
#define QSCALE (0.08838834764831843f * 1.4426950408889634f)

typedef __attribute__((ext_vector_type(8))) short bf16x8;
typedef __attribute__((ext_vector_type(4))) float f32x4;
typedef unsigned short u16;
typedef unsigned int u32;

__device__ __forceinline__ u16 f2bf(float f) {
    union { float f; u32 u; } x; x.f = f;
    u32 r = x.u + 0x7fff + ((x.u >> 16) & 1);   // RNE
    return (u16)(r >> 16);
}
// HW packed f32->bf16 (RNE), 1 instr for 2 values: lo=bf16(a), hi=bf16(b)
__device__ __forceinline__ u32 cvtpk_bf16(float a, float b) {
    u32 r;
    asm("v_cvt_pk_bf16_f32 %0, %1, %2" : "=v"(r) : "v"(a), "v"(b));
    return r;
}

__device__ __forceinline__ void gload_lds16(const void* g, void* l) {
    __builtin_amdgcn_global_load_lds(
        (const __attribute__((address_space(1))) u32*)g,
        (__attribute__((address_space(3))) u32*)l, 16, 0, 0);
}

// raw workgroup barrier: NO implicit vmcnt/lgkmcnt drain (unlike __syncthreads).
// memory clobber pins compiler ordering of LDS/global ops across it.
#define RBAR asm volatile("s_barrier" ::: "memory")

// ---------------------------------------------------------------------------
// Fused fp32->bf16 cast of all 5 tensors. Block-granular segments, 1024 el/blk.
// ---------------------------------------------------------------------------
#define NB_X  8192      // B*S*E / 1024
#define NB_QO 4096      // E*E / 1024
#define NB_KV 1024      // KVN*E / 1024
__global__ __launch_bounds__(256) void cast_all(const float* __restrict__ x,
                                                const float* __restrict__ wq,
                                                const float* __restrict__ wk,
                                                const float* __restrict__ wv,
                                                const float* __restrict__ wo,
                                                u16* __restrict__ xb, u16* __restrict__ wqb,
                                                u16* __restrict__ wkb, u16* __restrict__ wvb,
                                                u16* __restrict__ wob) {
    int bid = blockIdx.x;
    const float* src; u16* dst; int off;
    if (bid < NB_X)                       { src = x;  dst = xb;  off = bid * 1024; }
    else if (bid < NB_X + NB_QO)          { src = wq; dst = wqb; off = (bid - NB_X) * 1024; }
    else if (bid < NB_X + NB_QO + NB_KV)  { src = wk; dst = wkb; off = (bid - NB_X - NB_QO) * 1024; }
    else if (bid < NB_X + NB_QO + 2*NB_KV){ src = wv; dst = wvb; off = (bid - NB_X - NB_QO - NB_KV) * 1024; }
    else                                  { src = wo; dst = wob; off = (bid - NB_X - NB_QO - 2*NB_KV) * 1024; }
    int i = off + threadIdx.x * 4;
    float4 v = *(const float4*)&src[i];
    ushort4 o;
    o.x = f2bf(v.x); o.y = f2bf(v.y); o.z = f2bf(v.z); o.w = f2bf(v.w);
    *(ushort4*)&dst[i] = o;
}

// ---------------------------------------------------------------------------
// Deep-pipelined MFMA GEMM: C[M,N] = A[M,K] @ B[N,K]^T, bf16 in, fp32 acc.
// BM=256 rows, BN=256 or 128, BK=32, 512 threads = 8 waves (2M x 4N),
// per-wave output 128 x BN/4 (8 x NF fragments of 16x16).
// TRIPLE-buffered LDS slots; stage(t+2) issued at iter top; counted
// s_waitcnt vmcnt(2*LPT) + raw s_barrier (T4: 2 tiles of loads stay in
// flight across every barrier, never drained in the main loop). Per K-tile:
// 4 phases (2 for BN=128) of {ds_read subtile; s_barrier; setprio(1);
// 8 MFMA; setprio(0); s_barrier} (T3+T5). Tile-t's FIRST ds_read is after
// the confirming barrier (cross-wave DMA visibility: every wave did
// vmcnt(2*LPT) -> own tile-t loads landed -> barrier -> all landed).
// BK=32 => 64-B LDS rows: b128 frag reads spread over all 32 banks
// (bank = row-parity*16 + chunk*4) -> conflict-free without swizzle,
// and staging stays linear global_load_lds.
// MODE 0: fp32 row-major C.  MODE 5: fused QKV epilogue (same as before).
// ---------------------------------------------------------------------------
template <int MODE, int BN>
__global__ __launch_bounds__(512, 2) void gemm_8ph(const u16* __restrict__ A,
                                                   const u16* __restrict__ B,
                                                   void* __restrict__ Cv,
                                                   void* __restrict__ Cv2,
                                                   void* __restrict__ Cv3,
                                                   int M, int N, int K) {
    constexpr int BM = 256, BK = 32;
    constexpr int NF  = BN / 64;                  // B frags per wave (n-dim)
    constexpr int AIT = (BM * BK / 8) / 512;      // A stage loads/thread = 2
    constexpr int BIT = (BN * BK / 8) / 512;      // B stage loads/thread = 2|1
    constexpr int LPT = AIT + BIT;                // loads/thread/tile = 4|3
    __shared__ __align__(16) u16 As[3][BM * BK];
    __shared__ __align__(16) u16 Bs[3][BN * BK];

    const int tid  = threadIdx.x;
    const int w    = tid >> 6;
    const int lane = tid & 63;
    const int l16  = lane & 15;
    const int quad = lane >> 4;
    const int wm   = (w >> 2) * 128;
    const int wn   = (w & 3) * (BN / 4);
    const int m0   = blockIdx.y * BM;
    const int n0   = blockIdx.x * BN;
    const int nt   = K / BK;

    auto stage = [&](int t, int s) {
        const int kO = t * BK;
#pragma unroll
        for (int it = 0; it < AIT; ++it) {
            int ci = it * 512 + tid;              // chunk (16B) index, 1024 total
            gload_lds16(A + (size_t)(m0 + (ci >> 2)) * K + kO + (ci & 3) * 8,
                        &As[s][(size_t)(it * 512 + (tid & 448)) * 8]);
        }
#pragma unroll
        for (int it = 0; it < BIT; ++it) {
            int ci = it * 512 + tid;
            gload_lds16(B + (size_t)(n0 + (ci >> 2)) * K + kO + (ci & 3) * 8,
                        &Bs[s][(size_t)(it * 512 + (tid & 448)) * 8]);
        }
    };

    f32x4 acc[8][NF];
#pragma unroll
    for (int i = 0; i < 8; ++i)
#pragma unroll
        for (int j = 0; j < NF; ++j) acc[i][j] = (f32x4){0.f, 0.f, 0.f, 0.f};

    stage(0, 0);
    stage(1, 1);
    int s = 0;

    for (int t = 0; t < nt; ++t) {
        int s2 = s + 2; if (s2 >= 3) s2 -= 3;
        if (t + 2 < nt) stage(t + 2, s2);

        // counted waits: own-wave tile-t loads landed; barrier makes it global
        if (t + 2 < nt) {
            asm volatile("s_waitcnt vmcnt(%0)" :: "i"(2 * LPT) : "memory");
        } else if (t + 1 < nt) {
            asm volatile("s_waitcnt vmcnt(%0)" :: "i"(LPT) : "memory");
        } else {
            asm volatile("s_waitcnt vmcnt(0)" ::: "memory");
        }
        RBAR;                                     // tile t fully visible in LDS

        const u16* as = As[s];
        const u16* bs = Bs[s];
        bf16x8 af[8], bf[NF];

        // ---- phase 0: A rows 0-63 (frags 0-3) x B frags 0-1 ----
#pragma unroll
        for (int i = 0; i < 4; ++i)
            af[i] = *(const bf16x8*)&as[(wm + i * 16 + l16) * 32 + quad * 8];
#pragma unroll
        for (int j = 0; j < 2; ++j)
            bf[j] = *(const bf16x8*)&bs[(wn + j * 16 + l16) * 32 + quad * 8];
        __builtin_amdgcn_s_setprio(1);
#pragma unroll
        for (int i = 0; i < 4; ++i)
#pragma unroll
            for (int j = 0; j < 2; ++j)
                acc[i][j] = __builtin_amdgcn_mfma_f32_16x16x32_bf16(af[i], bf[j], acc[i][j], 0, 0, 0);
        __builtin_amdgcn_s_setprio(0);
        RBAR;

        if constexpr (NF == 4) {
            // ---- phase 1: A frags 0-3 x B frags 2-3 ----
#pragma unroll
            for (int j = 2; j < 4; ++j)
                bf[j] = *(const bf16x8*)&bs[(wn + j * 16 + l16) * 32 + quad * 8];
            RBAR;
            __builtin_amdgcn_s_setprio(1);
#pragma unroll
            for (int i = 0; i < 4; ++i)
#pragma unroll
                for (int j = 2; j < 4; ++j)
                    acc[i][j] = __builtin_amdgcn_mfma_f32_16x16x32_bf16(af[i], bf[j], acc[i][j], 0, 0, 0);
            __builtin_amdgcn_s_setprio(0);
            RBAR;
        }

        // ---- phase 2: A rows 64-127 (frags 4-7) x B frags 0-1 ----
#pragma unroll
        for (int i = 4; i < 8; ++i)
            af[i] = *(const bf16x8*)&as[(wm + i * 16 + l16) * 32 + quad * 8];
        RBAR;
        __builtin_amdgcn_s_setprio(1);
#pragma unroll
        for (int i = 4; i < 8; ++i)
#pragma unroll
            for (int j = 0; j < 2; ++j)
                acc[i][j] = __builtin_amdgcn_mfma_f32_16x16x32_bf16(af[i], bf[j], acc[i][j], 0, 0, 0);
        __builtin_amdgcn_s_setprio(0);
        RBAR;

        if constexpr (NF == 4) {
            // ---- phase 3: A frags 4-7 x B frags 2-3 ----
            __builtin_amdgcn_s_setprio(1);
#pragma unroll
            for (int i = 4; i < 8; ++i)
#pragma unroll
                for (int j = 2; j < 4; ++j)
                    acc[i][j] = __builtin_amdgcn_mfma_f32_16x16x32_bf16(af[i], bf[j], acc[i][j], 0, 0, 0);
            __builtin_amdgcn_s_setprio(0);
            RBAR;
        }

        s = s + 1; if (s >= 3) s = 0;
    }

    // ---- epilogue ----
    if (MODE == 0) {
        float* C = (float*)Cv;
#pragma unroll
        for (int i = 0; i < 8; ++i)
#pragma unroll
            for (int j = 0; j < NF; ++j)
#pragma unroll
                for (int reg = 0; reg < 4; ++reg)
                    C[(size_t)(m0 + wm + i * 16 + quad * 4 + reg) * N + n0 + wn + j * 16 + l16] =
                        acc[i][j][reg];
    } else {   // MODE 5
        if (n0 < 2048) {
            u16* C = (u16*)Cv;   // Qg [M][2048], QSCALE folded in
#pragma unroll
            for (int i = 0; i < 8; ++i)
#pragma unroll
                for (int j = 0; j < NF; ++j)
#pragma unroll
                    for (int reg = 0; reg < 4; ++reg)
                        C[(size_t)(m0 + wm + i * 16 + quad * 4 + reg) * 2048 + n0 + wn + j * 16 + l16] =
                            f2bf(acc[i][j][reg] * QSCALE);
        } else if (n0 < 2560) {
            u16* C = (u16*)Cv2;  // Kg [M][512]
            const int nb = n0 - 2048;
#pragma unroll
            for (int i = 0; i < 8; ++i)
#pragma unroll
                for (int j = 0; j < NF; ++j)
#pragma unroll
                    for (int reg = 0; reg < 4; ++reg)
                        C[(size_t)(m0 + wm + i * 16 + quad * 4 + reg) * KVN + nb + wn + j * 16 + l16] =
                            f2bf(acc[i][j][reg]);
        } else {
            u16* C2 = (u16*)Cv3;  // Vt [(b*KVN + d)][S]
            const int db = n0 - 2560;
#pragma unroll
            for (int i = 0; i < 8; ++i) {
                const int m = m0 + wm + i * 16 + quad * 4;
                const int bb = m >> 11;
                const int sR = m & (SS - 1);
#pragma unroll
                for (int j = 0; j < NF; ++j) {
                    const int d = db + wn + j * 16 + l16;
                    ushort4 p;
                    p.x = f2bf(acc[i][j][0]); p.y = f2bf(acc[i][j][1]);
                    p.z = f2bf(acc[i][j][2]); p.w = f2bf(acc[i][j][3]);
                    *(ushort4*)&C2[((size_t)(bb * KVN + d)) * SS + sR] = p;
                }
            }
        }
    }
}

// ---------------------------------------------------------------------------
// Flash-style causal GQA attention, bf16 MFMA, Q-tile 128 rows.
// IN-BLOCK SPLIT-K: 512 threads = 2 wave-groups of 4 waves; group g handles
// keys [g*(qc+1)*64, (g+1)*(qc+1)*64) -- equal tile/barrier counts. Partials
// merged in-block via LDS flash merge. (Round-3 kernel, unchanged.)
// ---------------------------------------------------------------------------
__global__ __launch_bounds__(512, 2) void attn_mfma(const u16* __restrict__ Qg,
                                                    const u16* __restrict__ Kg,
                                                    const u16* __restrict__ VtG,
                                                    u16* __restrict__ ctx) {
    __shared__ __align__(16) u16 Ks[2][2][64 * 128];   // [grp][buf] 64 KB
    __shared__ __align__(16) u16 Vt[2][128 * 64];      // [grp] 32 KB
    __shared__ __align__(16) u16 Ps[2][128 * 64];      // [grp] 32 KB

    const int tid  = threadIdx.x;        // 0..511
    const int w    = tid >> 6;           // 0..7
    const int grp  = w >> 2;             // wave-group: 0 = low keys, 1 = high keys
    const int wq   = w & 3;              // q-row wave within group
    const int tg   = tid & 255;          // tid within group
    const int lane = tid & 63;
    const int l16  = lane & 15;
    const int quad = lane >> 4;
    const int sw   = l16 & 7;            // swizzle key for all fragment rows

    // task map: blocks f and f+256 get qc summing to 15 (small first, then big)
    const int f    = blockIdx.x;
    const int half = f >> 8;
    const int u    = f & 255;
    const int h    = u & 15;
    const int w2   = u >> 4;
    const int b    = w2 & 1;
    const int j    = w2 >> 1;                  // 0..7
    const int qc   = half ? (15 - j) : j;      // 0..15
    const int kvh  = h / GG;
    const int q0   = qc * 128;
    const int NT   = qc + 1;                   // k-tiles per group (equal!)

    const size_t kgbase = (size_t)(b * SS) * KVN + kvh * DD;
    const size_t vgbase = (size_t)(b * KVN + kvh * DD) * SS;

    const int myq[2] = { q0 + wq * 16 + l16, q0 + 64 + wq * 16 + l16 };

    // ---- Q fragments direct from global ----
    bf16x8 Qa[2][4];
#pragma unroll
    for (int mi = 0; mi < 2; ++mi)
#pragma unroll
        for (int kd = 0; kd < 4; ++kd)
            Qa[mi][kd] = *(const bf16x8*)(Qg + (size_t)(b * SS + myq[mi]) * EE
                                          + h * DD + kd * 32 + quad * 8);

    float m_i[2] = {-INFINITY, -INFINITY};
    float l_i[2] = {0.f, 0.f};          // per-lane partials, reduced at the end
    f32x4 acc_o[2][8];
#pragma unroll
    for (int mi = 0; mi < 2; ++mi)
#pragma unroll
        for (int dt = 0; dt < 8; ++dt) acc_o[mi][dt] = (f32x4){0.f, 0.f, 0.f, 0.f};

    // ---- swizzled async stages (per group, 4 waves each) ----
    auto stageK = [&](int gkt, int buf) {
#pragma unroll
        for (int it = 0; it < 4; ++it) {
            int ci = it * 256 + tg;           // chunk slot (16B units), 1024 total
            int r = ci >> 4, pp = ci & 15;
            int c = (pp & 8) | ((pp ^ r) & 7);
            gload_lds16(Kg + kgbase + (size_t)(gkt * 64 + r) * KVN + c * 8,
                        &Ks[grp][buf][(size_t)(it * 256 + (tg & 192)) * 8]);
        }
    };
    auto stageV = [&](int gkt) {
#pragma unroll
        for (int it = 0; it < 4; ++it) {
            int ci = it * 256 + tg;
            int r = ci >> 3, pp = ci & 7;
            int c = (pp ^ r) & 7;
            gload_lds16(VtG + vgbase + (size_t)r * SS + gkt * 64 + c * 8,
                        &Vt[grp][(size_t)(it * 256 + (tg & 192)) * 8]);
        }
    };

    stageK(grp * NT, 0);
    int buf = 0;

    for (int kt = 0; kt < NT; ++kt) {
        const int gkt = grp * NT + kt;        // global 64-key tile index
        const int gk0 = gkt * 64;             // first key of this tile

        __syncthreads();                      // B1: K(kt) landed; V region free
        stageV(gkt);
        if (kt + 1 < NT) stageK(gkt + 1, buf ^ 1);

        // per-mi status (wave-uniform): fully-masked / diagonal
        bool skip[2], diag[2];
#pragma unroll
        for (int mi = 0; mi < 2; ++mi) {
            const int lo = q0 + mi * 64;
            skip[mi] = (gk0 > lo + 63);
            diag[mi] = (!skip[mi]) && (gk0 + 63 > lo);
        }

        const u16* kb_base = Ks[grp][buf];

        // ---- S^T = K Q^T : lane q=l16, k = gk0 + kkt*16 + quad*4 + reg ----
        f32x4 sc[2][4];
#pragma unroll
        for (int mi = 0; mi < 2; ++mi)
#pragma unroll
            for (int kkt = 0; kkt < 4; ++kkt) sc[mi][kkt] = (f32x4){0.f, 0.f, 0.f, 0.f};
        __builtin_amdgcn_s_setprio(1);
#pragma unroll
        for (int kkt = 0; kkt < 4; ++kkt) {
            const int R = kkt * 16 + l16;
            bf16x8 kb[4];
#pragma unroll
            for (int kd = 0; kd < 4; ++kd) {
                int c = kd * 4 + quad;
                int pp = (c & 8) | ((c ^ sw) & 7);
                kb[kd] = *(const bf16x8*)&kb_base[(R * 16 + pp) * 8];
            }
            if (!skip[1])
#pragma unroll
                for (int kd = 0; kd < 4; ++kd)
                    sc[1][kkt] = __builtin_amdgcn_mfma_f32_16x16x32_bf16(kb[kd], Qa[1][kd], sc[1][kkt], 0, 0, 0);
            if (!skip[0])
#pragma unroll
                for (int kd = 0; kd < 4; ++kd)
                    sc[0][kkt] = __builtin_amdgcn_mfma_f32_16x16x32_bf16(kb[kd], Qa[0][kd], sc[0][kkt], 0, 0, 0);
        }
        __builtin_amdgcn_s_setprio(0);

        // ---- per-lane online softmax (log2 domain), vote-gated rescale ----
#pragma unroll
        for (int mi = 0; mi < 2; ++mi) {
            if (skip[mi]) continue;
            if (diag[mi]) {
                const int kb0 = gk0 + quad * 4;
#pragma unroll
                for (int kkt = 0; kkt < 4; ++kkt)
#pragma unroll
                    for (int reg = 0; reg < 4; ++reg)
                        if (kb0 + kkt * 16 + reg > myq[mi]) sc[mi][kkt][reg] = -INFINITY;
            }
            float rowmax = -INFINITY;
#pragma unroll
            for (int kkt = 0; kkt < 4; ++kkt)
                rowmax = fmaxf(rowmax,
                               fmaxf(fmaxf(sc[mi][kkt][0], sc[mi][kkt][1]),
                                     fmaxf(sc[mi][kkt][2], sc[mi][kkt][3])));

            if (__any(rowmax > m_i[mi] + 8.0f)) {   // wave-uniform, rare after warmup
                float gmax = fmaxf(rowmax, __shfl_xor(rowmax, 16, 64));
                gmax = fmaxf(gmax, __shfl_xor(gmax, 32, 64));
                float mnew = fmaxf(m_i[mi], gmax);
                float al = exp2f(m_i[mi] - mnew);
                m_i[mi] = mnew;
                l_i[mi] *= al;
#pragma unroll
                for (int dt = 0; dt < 8; ++dt)
#pragma unroll
                    for (int reg = 0; reg < 4; ++reg)
                        acc_o[mi][dt][reg] *= al;
            }

            float rsum = 0.f;
#pragma unroll
            for (int kkt = 0; kkt < 4; ++kkt)
#pragma unroll
                for (int reg = 0; reg < 4; ++reg) {
                    float p = exp2f(sc[mi][kkt][reg] - m_i[mi]);   // bounded by 2^8
                    sc[mi][kkt][reg] = p;
                    rsum += p;
                }
            l_i[mi] += rsum;

            // swizzled packed P^T write via HW cvt_pk
            const int prow = mi * 64 + wq * 16 + l16;
#pragma unroll
            for (int kkt = 0; kkt < 4; ++kkt) {
                int ch = (kkt * 2 + (quad >> 1)) ^ sw;
                uint2 pk;
                pk.x = cvtpk_bf16(sc[mi][kkt][0], sc[mi][kkt][1]);
                pk.y = cvtpk_bf16(sc[mi][kkt][2], sc[mi][kkt][3]);
                *(uint2*)&Ps[grp][(prow * 8 + ch) * 8 + (quad & 1) * 4] = pk;
            }
        }

        __syncthreads();                      // B2: V(kt) landed (all waves' DMA)

        // ---- O^T += V^T P^T ----
        const u16* vb_base = Vt[grp];
        __builtin_amdgcn_s_setprio(1);
#pragma unroll
        for (int ks = 0; ks < 2; ++ks) {
            const int pc = (ks * 4 + quad) ^ sw;
            bf16x8 pb1, pb0;
            if (!skip[1]) pb1 = *(const bf16x8*)&Ps[grp][((64 + wq * 16 + l16) * 8 + pc) * 8];
            if (!skip[0]) pb0 = *(const bf16x8*)&Ps[grp][((wq * 16 + l16) * 8 + pc) * 8];
#pragma unroll
            for (int dt = 0; dt < 8; ++dt) {
                bf16x8 va = *(const bf16x8*)&vb_base[((dt * 16 + l16) * 8 + pc) * 8];
                if (!skip[1])
                    acc_o[1][dt] = __builtin_amdgcn_mfma_f32_16x16x32_bf16(va, pb1, acc_o[1][dt], 0, 0, 0);
                if (!skip[0])
                    acc_o[0][dt] = __builtin_amdgcn_mfma_f32_16x16x32_bf16(va, pb0, acc_o[0][dt], 0, 0, 0);
            }
        }
        __builtin_amdgcn_s_setprio(0);
        buf ^= 1;
    }

    // ---- in-block flash merge of the two key-halves ----
    __syncthreads();                          // B3: all compute done; LDS free
    float* dumpO = (float*)&Ks[0][0][0];      // 4 waves * 64 lanes * 64 f32 = 64 KB
    float* dumpML = (float*)&Ps[1][0];        // 4 waves * 64 lanes * 4 f32 = 4 KB
    if (grp == 1) {
        const int base = (wq * 64 + lane) * 64;
#pragma unroll
        for (int mi = 0; mi < 2; ++mi)
#pragma unroll
            for (int dt = 0; dt < 8; ++dt)
                *(f32x4*)&dumpO[base + mi * 32 + dt * 4] = acc_o[mi][dt];
        const int mb = (wq * 64 + lane) * 4;
        dumpML[mb + 0] = m_i[0];
        dumpML[mb + 1] = m_i[1];
        dumpML[mb + 2] = l_i[0];
        dumpML[mb + 3] = l_i[1];
    }
    __syncthreads();                          // B4: dump visible
    if (grp == 0) {
        const int base = (wq * 64 + lane) * 64;
        const int mb = (wq * 64 + lane) * 4;
#pragma unroll
        for (int mi = 0; mi < 2; ++mi) {
            const float m1 = dumpML[mb + mi];
            const float l1 = dumpML[mb + 2 + mi];
            const float ms = fmaxf(m_i[mi], m1);
            const float a0 = exp2f(m_i[mi] - ms);   // 0 if m_i = -inf
            const float a1 = exp2f(m1 - ms);        // 0 if m1  = -inf
            float lt = l_i[mi] * a0 + l1 * a1;
            lt += __shfl_xor(lt, 16, 64);
            lt += __shfl_xor(lt, 32, 64);
            const float linv = 1.f / lt;
            u16* dst = ctx + (size_t)(b * SS + myq[mi]) * EE + h * DD;
#pragma unroll
            for (int dt = 0; dt < 8; ++dt) {
                f32x4 o1 = *(const f32x4*)&dumpO[base + mi * 32 + dt * 4];
                uint2 o;
                o.x = cvtpk_bf16((acc_o[mi][dt][0] * a0 + o1[0] * a1) * linv,
                                 (acc_o[mi][dt][1] * a0 + o1[1] * a1) * linv);
                o.y = cvtpk_bf16((acc_o[mi][dt][2] * a0 + o1[2] * a1) * linv,
                                 (acc_o[mi][dt][3] * a0 + o1[3] * a1) * linv);
                *(uint2*)&dst[dt * 16 + quad * 4] = o;
            }
        }
    }
}

// ---------------------------------------------------------------------------
extern "C" void kernel_launch(void* const* d_in, const int* in_sizes, int n_in,
                              void* d_out, int out_size, void* d_ws, size_t ws_size,
                              hipStream_t stream) {
    const float* x  = (const float*)d_in[0];
    const float* Wq = (const float*)d_in[1];
    const float* Wk = (const float*)d_in[2];
    const float* Wv = (const float*)d_in[3];
    const float* Wo = (const float*)d_in[4];
    float* out = (float*)d_out;

    const int M = BB * SS;                        // 4096
    u16* xb  = (u16*)d_ws;                        // M*E
    u16* Wqb = xb  + (size_t)M * EE;              // E*E   } contiguous ->
    u16* Wkb = Wqb + (size_t)EE * EE;             // KVN*E }  single 3072-row
    u16* Wvb = Wkb + (size_t)KVN * EE;            // KVN*E }  B matrix
    u16* Wob = Wvb + (size_t)KVN * EE;            // E*E
    u16* Qg  = Wob + (size_t)EE * EE;             // M*E (pre-scaled by QSCALE)
    u16* Kg  = Qg  + (size_t)M * EE;              // M*KVN
    u16* VtG = Kg  + (size_t)M * KVN;             // M*KVN (transposed)
    u16* ctx = VtG + (size_t)M * KVN;             // M*E

    dim3 blk(256);
    cast_all<<<dim3(NB_X + NB_QO + 2 * NB_KV + NB_QO), blk, 0, stream>>>(
        x, Wq, Wk, Wv, Wo, xb, Wqb, Wkb, Wvb, Wob);

    // fused QKV projection: B = [Wq;Wk;Wv] (3072 x 2048), 256x256 tiles
    gemm_8ph<5, 256><<<dim3(3072 / 256, M / 256), dim3(512), 0, stream>>>(
        xb, Wqb, Qg, Kg, VtG, M, 3072, EE);
    attn_mfma<<<dim3(512), dim3(512), 0, stream>>>(Qg, Kg, VtG, ctx);
    // output projection, 256x128 tiles (grid 16x16 = 256 blocks, full GPU)
    gemm_8ph<0, 128><<<dim3(EE / 128, M / 256), dim3(512), 0, stream>>>(
        ctx, Wob, out, nullptr, nullptr, M, EE, EE);
}

// Round 5
// 316.917 us; speedup vs baseline: 1.0815x; 1.0815x over previous
//
#include <hip/hip_runtime.h>
#include <math.h>

#define BB 2
#define SS 2048
#define EE 2048
#define HH 16
#define KVHH 4
#define DD 128
#define GG (HH / KVHH)
#define KVN (KVHH * DD)   // 512
#define SCALE 0.08838834764831843f
// SCALE * log2(e): scores land in log2 domain -> exp2f softmax
#define QSCALE (0.08838834764831843f * 1.4426950408889634f)

typedef __attribute__((ext_vector_type(8))) short bf16x8;
typedef __attribute__((ext_vector_type(4))) float f32x4;
typedef unsigned short u16;
typedef unsigned int u32;

__device__ __forceinline__ u16 f2bf(float f) {
    union { float f; u32 u; } x; x.f = f;
    u32 r = x.u + 0x7fff + ((x.u >> 16) & 1);   // RNE
    return (u16)(r >> 16);
}
// HW packed f32->bf16 (RNE), 1 instr for 2 values: lo=bf16(a), hi=bf16(b)
__device__ __forceinline__ u32 cvtpk_bf16(float a, float b) {
    u32 r;
    asm("v_cvt_pk_bf16_f32 %0, %1, %2" : "=v"(r) : "v"(a), "v"(b));
    return r;
}

__device__ __forceinline__ void gload_lds16(const void* g, void* l) {
    __builtin_amdgcn_global_load_lds(
        (const __attribute__((address_space(1))) u32*)g,
        (__attribute__((address_space(3))) u32*)l, 16, 0, 0);
}

// raw workgroup barrier: NO implicit vmcnt/lgkmcnt drain (unlike __syncthreads).
#define RBAR asm volatile("s_barrier" ::: "memory")

// ---------------------------------------------------------------------------
// Fused fp32->bf16 cast of all 5 tensors. Block-granular segments, 1024 el/blk.
// ---------------------------------------------------------------------------
#define NB_X  8192      // B*S*E / 1024
#define NB_QO 4096      // E*E / 1024
#define NB_KV 1024      // KVN*E / 1024
__global__ __launch_bounds__(256) void cast_all(const float* __restrict__ x,
                                                const float* __restrict__ wq,
                                                const float* __restrict__ wk,
                                                const float* __restrict__ wv,
                                                const float* __restrict__ wo,
                                                u16* __restrict__ xb, u16* __restrict__ wqb,
                                                u16* __restrict__ wkb, u16* __restrict__ wvb,
                                                u16* __restrict__ wob) {
    int bid = blockIdx.x;
    const float* src; u16* dst; int off;
    if (bid < NB_X)                       { src = x;  dst = xb;  off = bid * 1024; }
    else if (bid < NB_X + NB_QO)          { src = wq; dst = wqb; off = (bid - NB_X) * 1024; }
    else if (bid < NB_X + NB_QO + NB_KV)  { src = wk; dst = wkb; off = (bid - NB_X - NB_QO) * 1024; }
    else if (bid < NB_X + NB_QO + 2*NB_KV){ src = wv; dst = wvb; off = (bid - NB_X - NB_QO - NB_KV) * 1024; }
    else                                  { src = wo; dst = wob; off = (bid - NB_X - NB_QO - 2*NB_KV) * 1024; }
    int i = off + threadIdx.x * 4;
    float4 v = *(const float4*)&src[i];
    ushort4 o;
    o.x = f2bf(v.x); o.y = f2bf(v.y); o.z = f2bf(v.z); o.w = f2bf(v.w);
    *(ushort4*)&dst[i] = o;
}

// ---------------------------------------------------------------------------
// m201-template MFMA GEMM: C[M,N] = A[M,K] @ B[N,K]^T, bf16 in, fp32 acc.
// BM=BN=256, BK=64, 512 threads = 8 waves (2M x 4N), per-wave C 128x64
// (8 m-frags x 4 n-frags). LDS: A,B each [2 slot][2 half][128][64] bf16 =
// 128 KB total, slot = tile&1. Pair-unrolled loop: 8 phases / 2 K-tiles,
// 16 MFMA per phase. XOR swizzle (chunk ^= row&7, 8 chunks of 16B per row)
// applied BOTH sides: pre-swizzled global source in global_load_lds (linear
// LDS dest) + swizzled ds_read address -> b128 reads conflict-free (16 lanes
// spread over all 32 banks, 2-way = free). Counted vmcnt(4) ONLY at phase-4
// and phase-8 ends (T4); never drains in steady state. Staging windows
// verified: a slot's ds_reads are lgkm-drained before that phase's trailing
// barrier (MFMA waits the in-order LDS queue), so staging into the slot in
// the next phase is race-free; every half-tile has >=3 phases of flight.
//   stage map (pair j: tiles t0=2j slot0, t1=2j+1 slot1):
//     P0: B halves of t1 | P3: A halves of t0+2 | P4: B halves of t0+2 |
//     P7: A halves of t0+3;  vmcnt(4) @P3-end confirms t1, @P7-end confirms t0+2.
// MODE 0: fp32 row-major C.  MODE 5: fused QKV epilogue.
// ---------------------------------------------------------------------------
template <int MODE>
__global__ __launch_bounds__(512, 2) void gemm_8ph(const u16* __restrict__ A,
                                                   const u16* __restrict__ B,
                                                   void* __restrict__ Cv,
                                                   void* __restrict__ Cv2,
                                                   void* __restrict__ Cv3,
                                                   int M, int N, int K) {
    __shared__ __align__(16) u16 As[2][2][128 * 64];   // [slot][half] 64 KB
    __shared__ __align__(16) u16 Bs[2][2][128 * 64];   // [slot][half] 64 KB

    const int tid  = threadIdx.x;
    const int w    = tid >> 6;
    const int lane = tid & 63;
    const int l16  = lane & 15;
    const int quad = lane >> 4;
    const int sw   = l16 & 7;                 // swizzle key
    const int wm   = (w >> 2) * 128;          // wave M offset (selects A half)
    const int wn   = (w & 3) * 64;            // wave N offset
    const int ha   = w >> 2;                  // wave's A half
    const int hb   = (w & 3) >> 1;            // wave's B half
    const int nb   = wn & 127;                // row base within B half (0|64)
    const int m0   = blockIdx.y * 256;
    const int n0   = blockIdx.x * 256;
    const int nt   = K / 64;                  // K-tiles (even: 2048/64 = 32)

    bf16x8 a[8], b0[4], b1[4];
    f32x4 acc[8][4];
#pragma unroll
    for (int i = 0; i < 8; ++i)
#pragma unroll
        for (int j = 0; j < 4; ++j) acc[i][j] = (f32x4){0.f, 0.f, 0.f, 0.f};

    // ---- staging: pre-swizzled global source, linear LDS dest ----
    auto stA = [&](int t, int half) {
#pragma unroll
        for (int it = 0; it < 2; ++it) {
            int ci = it * 512 + tid;              // linear chunk slot (16B), 1024/half
            int r  = ci >> 3;                     // row 0..127
            int c  = (ci & 7) ^ (r & 7);          // source chunk for this slot
            gload_lds16(A + (size_t)(m0 + half * 128 + r) * K + t * 64 + c * 8,
                        &As[t & 1][half][(size_t)(it * 512 + (tid & 448)) * 8]);
        }
    };
    auto stB = [&](int t, int half) {
#pragma unroll
        for (int it = 0; it < 2; ++it) {
            int ci = it * 512 + tid;
            int r  = ci >> 3;
            int c  = (ci & 7) ^ (r & 7);
            gload_lds16(B + (size_t)(n0 + half * 128 + r) * K + t * 64 + c * 8,
                        &Bs[t & 1][half][(size_t)(it * 512 + (tid & 448)) * 8]);
        }
    };

    // ---- swizzled fragment reads (wave reads only its own half) ----
    auto ldA = [&](int slot, int ih) {           // ih: 0 -> m-frags 0-3, 1 -> 4-7
#pragma unroll
        for (int i = 0; i < 4; ++i)
#pragma unroll
            for (int kk = 0; kk < 2; ++kk) {
                int r = (ih * 4 + i) * 16 + l16;
                int c = (kk * 4 + quad) ^ sw;
                a[i * 2 + kk] = *(const bf16x8*)&As[slot][ha][(r * 8 + c) * 8];
            }
    };
    auto ldB = [&](int slot, int jh, bf16x8* bb) {  // jh: 0 -> n-frags 0-1, 1 -> 2-3
#pragma unroll
        for (int jn = 0; jn < 2; ++jn)
#pragma unroll
            for (int kk = 0; kk < 2; ++kk) {
                int r = nb + (jh * 2 + jn) * 16 + l16;
                int c = (kk * 4 + quad) ^ sw;
                bb[jn * 2 + kk] = *(const bf16x8*)&Bs[slot][hb][(r * 8 + c) * 8];
            }
    };
    auto mmac = [&](int ih, int jh, bf16x8* bb) {   // 16 MFMA: one C-quadrant x K=64
        __builtin_amdgcn_s_setprio(1);
#pragma unroll
        for (int kk = 0; kk < 2; ++kk)
#pragma unroll
            for (int i = 0; i < 4; ++i)
#pragma unroll
                for (int jn = 0; jn < 2; ++jn)
                    acc[ih * 4 + i][jh * 2 + jn] = __builtin_amdgcn_mfma_f32_16x16x32_bf16(
                        a[i * 2 + kk], bb[jn * 2 + kk], acc[ih * 4 + i][jh * 2 + jn], 0, 0, 0);
        __builtin_amdgcn_s_setprio(0);
    };

    // ---- prologue: tile0 (A+B), tile1 (A); confirm tile0 (4 outstanding) ----
    stA(0, 0); stA(0, 1); stB(0, 0); stB(0, 1);
    stA(1, 0); stA(1, 1);
    asm volatile("s_waitcnt vmcnt(4)" ::: "memory");
    RBAR;

    for (int t0 = 0; t0 < nt; t0 += 2) {
        const int t1 = t0 + 1;
        const bool st2 = (t0 + 2 < nt), st3 = (t0 + 3 < nt);

        // ======== tile t0 (slot 0) ========
        // P0: reads a03,b01(t0); stage B halves of t1 (slot1: free since prev P6)
        ldA(0, 0); ldB(0, 0, b0);
        stB(t1, 0); stB(t1, 1);
        RBAR; mmac(0, 0, b0); RBAR;
        // P1
        ldB(0, 1, b1);
        RBAR; mmac(0, 1, b1); RBAR;
        // P2
        ldA(0, 1);
        RBAR; mmac(1, 1, b1); RBAR;
        // P3: stage A halves of t0+2 (slot0: all reads drained by P2 barrier)
        if (st2) { stA(t0 + 2, 0); stA(t0 + 2, 1); }
        RBAR; mmac(1, 0, b0);
        if (st2) { asm volatile("s_waitcnt vmcnt(4)" ::: "memory"); }
        else     { asm volatile("s_waitcnt vmcnt(0)" ::: "memory"); }
        RBAR;                                    // tile t1 confirmed

        // ======== tile t1 (slot 1) ========
        // P4: reads a03,b01(t1); stage B halves of t0+2
        ldA(1, 0); ldB(1, 0, b0);
        if (st2) { stB(t0 + 2, 0); stB(t0 + 2, 1); }
        RBAR; mmac(0, 0, b0); RBAR;
        // P5
        ldB(1, 1, b1);
        RBAR; mmac(0, 1, b1); RBAR;
        // P6
        ldA(1, 1);
        RBAR; mmac(1, 1, b1); RBAR;
        // P7: stage A halves of t0+3 (slot1 reads drained by P6 barrier)
        if (st3) { stA(t0 + 3, 0); stA(t0 + 3, 1); }
        RBAR; mmac(1, 0, b0);
        if (st3) { asm volatile("s_waitcnt vmcnt(4)" ::: "memory"); }
        else     { asm volatile("s_waitcnt vmcnt(0)" ::: "memory"); }
        RBAR;                                    // tile t0+2 confirmed
    }

    // ---- epilogue ----
    if (MODE == 0) {
        float* C = (float*)Cv;
#pragma unroll
        for (int i = 0; i < 8; ++i)
#pragma unroll
            for (int j = 0; j < 4; ++j)
#pragma unroll
                for (int reg = 0; reg < 4; ++reg)
                    C[(size_t)(m0 + wm + i * 16 + quad * 4 + reg) * N + n0 + wn + j * 16 + l16] =
                        acc[i][j][reg];
    } else {   // MODE 5
        if (n0 < 2048) {
            u16* C = (u16*)Cv;   // Qg [M][2048], QSCALE folded in
#pragma unroll
            for (int i = 0; i < 8; ++i)
#pragma unroll
                for (int j = 0; j < 4; ++j)
#pragma unroll
                    for (int reg = 0; reg < 4; ++reg)
                        C[(size_t)(m0 + wm + i * 16 + quad * 4 + reg) * 2048 + n0 + wn + j * 16 + l16] =
                            f2bf(acc[i][j][reg] * QSCALE);
        } else if (n0 < 2560) {
            u16* C = (u16*)Cv2;  // Kg [M][512]
            const int nbq = n0 - 2048;
#pragma unroll
            for (int i = 0; i < 8; ++i)
#pragma unroll
                for (int j = 0; j < 4; ++j)
#pragma unroll
                    for (int reg = 0; reg < 4; ++reg)
                        C[(size_t)(m0 + wm + i * 16 + quad * 4 + reg) * KVN + nbq + wn + j * 16 + l16] =
                            f2bf(acc[i][j][reg]);
        } else {
            u16* C2 = (u16*)Cv3;  // Vt [(b*KVN + d)][S]
            const int db = n0 - 2560;
#pragma unroll
            for (int i = 0; i < 8; ++i) {
                const int m = m0 + wm + i * 16 + quad * 4;
                const int bb2 = m >> 11;
                const int sR  = m & (SS - 1);
#pragma unroll
                for (int j = 0; j < 4; ++j) {
                    const int d = db + wn + j * 16 + l16;
                    ushort4 p;
                    p.x = f2bf(acc[i][j][0]); p.y = f2bf(acc[i][j][1]);
                    p.z = f2bf(acc[i][j][2]); p.w = f2bf(acc[i][j][3]);
                    *(ushort4*)&C2[((size_t)(bb2 * KVN + d)) * SS + sR] = p;
                }
            }
        }
    }
}

// ---------------------------------------------------------------------------
// Flash-style causal GQA attention, bf16 MFMA, Q-tile 128 rows.
// IN-BLOCK SPLIT-K: 512 threads = 2 wave-groups of 4 waves; group g handles
// keys [g*(qc+1)*64, (g+1)*(qc+1)*64). In-block LDS flash merge at the end.
// (Round-3 kernel, unchanged.)
// ---------------------------------------------------------------------------
__global__ __launch_bounds__(512, 2) void attn_mfma(const u16* __restrict__ Qg,
                                                    const u16* __restrict__ Kg,
                                                    const u16* __restrict__ VtG,
                                                    u16* __restrict__ ctx) {
    __shared__ __align__(16) u16 Ks[2][2][64 * 128];   // [grp][buf] 64 KB
    __shared__ __align__(16) u16 Vt[2][128 * 64];      // [grp] 32 KB
    __shared__ __align__(16) u16 Ps[2][128 * 64];      // [grp] 32 KB

    const int tid  = threadIdx.x;        // 0..511
    const int w    = tid >> 6;           // 0..7
    const int grp  = w >> 2;             // wave-group: 0 = low keys, 1 = high keys
    const int wq   = w & 3;              // q-row wave within group
    const int tg   = tid & 255;          // tid within group
    const int lane = tid & 63;
    const int l16  = lane & 15;
    const int quad = lane >> 4;
    const int sw   = l16 & 7;            // swizzle key for all fragment rows

    // task map: blocks f and f+256 get qc summing to 15 (small first, then big)
    const int f    = blockIdx.x;
    const int half = f >> 8;
    const int u    = f & 255;
    const int h    = u & 15;
    const int w2   = u >> 4;
    const int b    = w2 & 1;
    const int j    = w2 >> 1;                  // 0..7
    const int qc   = half ? (15 - j) : j;      // 0..15
    const int kvh  = h / GG;
    const int q0   = qc * 128;
    const int NT   = qc + 1;                   // k-tiles per group (equal!)

    const size_t kgbase = (size_t)(b * SS) * KVN + kvh * DD;
    const size_t vgbase = (size_t)(b * KVN + kvh * DD) * SS;

    const int myq[2] = { q0 + wq * 16 + l16, q0 + 64 + wq * 16 + l16 };

    // ---- Q fragments direct from global ----
    bf16x8 Qa[2][4];
#pragma unroll
    for (int mi = 0; mi < 2; ++mi)
#pragma unroll
        for (int kd = 0; kd < 4; ++kd)
            Qa[mi][kd] = *(const bf16x8*)(Qg + (size_t)(b * SS + myq[mi]) * EE
                                          + h * DD + kd * 32 + quad * 8);

    float m_i[2] = {-INFINITY, -INFINITY};
    float l_i[2] = {0.f, 0.f};          // per-lane partials, reduced at the end
    f32x4 acc_o[2][8];
#pragma unroll
    for (int mi = 0; mi < 2; ++mi)
#pragma unroll
        for (int dt = 0; dt < 8; ++dt) acc_o[mi][dt] = (f32x4){0.f, 0.f, 0.f, 0.f};

    // ---- swizzled async stages (per group, 4 waves each) ----
    auto stageK = [&](int gkt, int buf) {
#pragma unroll
        for (int it = 0; it < 4; ++it) {
            int ci = it * 256 + tg;           // chunk slot (16B units), 1024 total
            int r = ci >> 4, pp = ci & 15;
            int c = (pp & 8) | ((pp ^ r) & 7);
            gload_lds16(Kg + kgbase + (size_t)(gkt * 64 + r) * KVN + c * 8,
                        &Ks[grp][buf][(size_t)(it * 256 + (tg & 192)) * 8]);
        }
    };
    auto stageV = [&](int gkt) {
#pragma unroll
        for (int it = 0; it < 4; ++it) {
            int ci = it * 256 + tg;
            int r = ci >> 3, pp = ci & 7;
            int c = (pp ^ r) & 7;
            gload_lds16(VtG + vgbase + (size_t)r * SS + gkt * 64 + c * 8,
                        &Vt[grp][(size_t)(it * 256 + (tg & 192)) * 8]);
        }
    };

    stageK(grp * NT, 0);
    int buf = 0;

    for (int kt = 0; kt < NT; ++kt) {
        const int gkt = grp * NT + kt;        // global 64-key tile index
        const int gk0 = gkt * 64;             // first key of this tile

        __syncthreads();                      // B1: K(kt) landed; V region free
        stageV(gkt);
        if (kt + 1 < NT) stageK(gkt + 1, buf ^ 1);

        // per-mi status (wave-uniform): fully-masked / diagonal
        bool skip[2], diag[2];
#pragma unroll
        for (int mi = 0; mi < 2; ++mi) {
            const int lo = q0 + mi * 64;
            skip[mi] = (gk0 > lo + 63);
            diag[mi] = (!skip[mi]) && (gk0 + 63 > lo);
        }

        const u16* kb_base = Ks[grp][buf];

        // ---- S^T = K Q^T : lane q=l16, k = gk0 + kkt*16 + quad*4 + reg ----
        f32x4 sc[2][4];
#pragma unroll
        for (int mi = 0; mi < 2; ++mi)
#pragma unroll
            for (int kkt = 0; kkt < 4; ++kkt) sc[mi][kkt] = (f32x4){0.f, 0.f, 0.f, 0.f};
        __builtin_amdgcn_s_setprio(1);
#pragma unroll
        for (int kkt = 0; kkt < 4; ++kkt) {
            const int R = kkt * 16 + l16;
            bf16x8 kb[4];
#pragma unroll
            for (int kd = 0; kd < 4; ++kd) {
                int c = kd * 4 + quad;
                int pp = (c & 8) | ((c ^ sw) & 7);
                kb[kd] = *(const bf16x8*)&kb_base[(R * 16 + pp) * 8];
            }
            if (!skip[1])
#pragma unroll
                for (int kd = 0; kd < 4; ++kd)
                    sc[1][kkt] = __builtin_amdgcn_mfma_f32_16x16x32_bf16(kb[kd], Qa[1][kd], sc[1][kkt], 0, 0, 0);
            if (!skip[0])
#pragma unroll
                for (int kd = 0; kd < 4; ++kd)
                    sc[0][kkt] = __builtin_amdgcn_mfma_f32_16x16x32_bf16(kb[kd], Qa[0][kd], sc[0][kkt], 0, 0, 0);
        }
        __builtin_amdgcn_s_setprio(0);

        // ---- per-lane online softmax (log2 domain), vote-gated rescale ----
#pragma unroll
        for (int mi = 0; mi < 2; ++mi) {
            if (skip[mi]) continue;
            if (diag[mi]) {
                const int kb0 = gk0 + quad * 4;
#pragma unroll
                for (int kkt = 0; kkt < 4; ++kkt)
#pragma unroll
                    for (int reg = 0; reg < 4; ++reg)
                        if (kb0 + kkt * 16 + reg > myq[mi]) sc[mi][kkt][reg] = -INFINITY;
            }
            float rowmax = -INFINITY;
#pragma unroll
            for (int kkt = 0; kkt < 4; ++kkt)
                rowmax = fmaxf(rowmax,
                               fmaxf(fmaxf(sc[mi][kkt][0], sc[mi][kkt][1]),
                                     fmaxf(sc[mi][kkt][2], sc[mi][kkt][3])));

            if (__any(rowmax > m_i[mi] + 8.0f)) {   // wave-uniform, rare after warmup
                float gmax = fmaxf(rowmax, __shfl_xor(rowmax, 16, 64));
                gmax = fmaxf(gmax, __shfl_xor(gmax, 32, 64));
                float mnew = fmaxf(m_i[mi], gmax);
                float al = exp2f(m_i[mi] - mnew);
                m_i[mi] = mnew;
                l_i[mi] *= al;
#pragma unroll
                for (int dt = 0; dt < 8; ++dt)
#pragma unroll
                    for (int reg = 0; reg < 4; ++reg)
                        acc_o[mi][dt][reg] *= al;
            }

            float rsum = 0.f;
#pragma unroll
            for (int kkt = 0; kkt < 4; ++kkt)
#pragma unroll
                for (int reg = 0; reg < 4; ++reg) {
                    float p = exp2f(sc[mi][kkt][reg] - m_i[mi]);   // bounded by 2^8
                    sc[mi][kkt][reg] = p;
                    rsum += p;
                }
            l_i[mi] += rsum;

            // swizzled packed P^T write via HW cvt_pk
            const int prow = mi * 64 + wq * 16 + l16;
#pragma unroll
            for (int kkt = 0; kkt < 4; ++kkt) {
                int ch = (kkt * 2 + (quad >> 1)) ^ sw;
                uint2 pk;
                pk.x = cvtpk_bf16(sc[mi][kkt][0], sc[mi][kkt][1]);
                pk.y = cvtpk_bf16(sc[mi][kkt][2], sc[mi][kkt][3]);
                *(uint2*)&Ps[grp][(prow * 8 + ch) * 8 + (quad & 1) * 4] = pk;
            }
        }

        __syncthreads();                      // B2: V(kt) landed (all waves' DMA)

        // ---- O^T += V^T P^T ----
        const u16* vb_base = Vt[grp];
        __builtin_amdgcn_s_setprio(1);
#pragma unroll
        for (int ks = 0; ks < 2; ++ks) {
            const int pc = (ks * 4 + quad) ^ sw;
            bf16x8 pb1, pb0;
            if (!skip[1]) pb1 = *(const bf16x8*)&Ps[grp][((64 + wq * 16 + l16) * 8 + pc) * 8];
            if (!skip[0]) pb0 = *(const bf16x8*)&Ps[grp][((wq * 16 + l16) * 8 + pc) * 8];
#pragma unroll
            for (int dt = 0; dt < 8; ++dt) {
                bf16x8 va = *(const bf16x8*)&vb_base[((dt * 16 + l16) * 8 + pc) * 8];
                if (!skip[1])
                    acc_o[1][dt] = __builtin_amdgcn_mfma_f32_16x16x32_bf16(va, pb1, acc_o[1][dt], 0, 0, 0);
                if (!skip[0])
                    acc_o[0][dt] = __builtin_amdgcn_mfma_f32_16x16x32_bf16(va, pb0, acc_o[0][dt], 0, 0, 0);
            }
        }
        __builtin_amdgcn_s_setprio(0);
        buf ^= 1;
    }

    // ---- in-block flash merge of the two key-halves ----
    __syncthreads();                          // B3: all compute done; LDS free
    float* dumpO = (float*)&Ks[0][0][0];      // 4 waves * 64 lanes * 64 f32 = 64 KB
    float* dumpML = (float*)&Ps[1][0];        // 4 waves * 64 lanes * 4 f32 = 4 KB
    if (grp == 1) {
        const int base = (wq * 64 + lane) * 64;
#pragma unroll
        for (int mi = 0; mi < 2; ++mi)
#pragma unroll
            for (int dt = 0; dt < 8; ++dt)
                *(f32x4*)&dumpO[base + mi * 32 + dt * 4] = acc_o[mi][dt];
        const int mb = (wq * 64 + lane) * 4;
        dumpML[mb + 0] = m_i[0];
        dumpML[mb + 1] = m_i[1];
        dumpML[mb + 2] = l_i[0];
        dumpML[mb + 3] = l_i[1];
    }
    __syncthreads();                          // B4: dump visible
    if (grp == 0) {
        const int base = (wq * 64 + lane) * 64;
        const int mb = (wq * 64 + lane) * 4;
#pragma unroll
        for (int mi = 0; mi < 2; ++mi) {
            const float m1 = dumpML[mb + mi];
            const float l1 = dumpML[mb + 2 + mi];
            const float ms = fmaxf(m_i[mi], m1);
            const float a0 = exp2f(m_i[mi] - ms);   // 0 if m_i = -inf
            const float a1 = exp2f(m1 - ms);        // 0 if m1  = -inf
            float lt = l_i[mi] * a0 + l1 * a1;
            lt += __shfl_xor(lt, 16, 64);
            lt += __shfl_xor(lt, 32, 64);
            const float linv = 1.f / lt;
            u16* dst = ctx + (size_t)(b * SS + myq[mi]) * EE + h * DD;
#pragma unroll
            for (int dt = 0; dt < 8; ++dt) {
                f32x4 o1 = *(const f32x4*)&dumpO[base + mi * 32 + dt * 4];
                uint2 o;
                o.x = cvtpk_bf16((acc_o[mi][dt][0] * a0 + o1[0] * a1) * linv,
                                 (acc_o[mi][dt][1] * a0 + o1[1] * a1) * linv);
                o.y = cvtpk_bf16((acc_o[mi][dt][2] * a0 + o1[2] * a1) * linv,
                                 (acc_o[mi][dt][3] * a0 + o1[3] * a1) * linv);
                *(uint2*)&dst[dt * 16 + quad * 4] = o;
            }
        }
    }
}

// ---------------------------------------------------------------------------
extern "C" void kernel_launch(void* const* d_in, const int* in_sizes, int n_in,
                              void* d_out, int out_size, void* d_ws, size_t ws_size,
                              hipStream_t stream) {
    const float* x  = (const float*)d_in[0];
    const float* Wq = (const float*)d_in[1];
    const float* Wk = (const float*)d_in[2];
    const float* Wv = (const float*)d_in[3];
    const float* Wo = (const float*)d_in[4];
    float* out = (float*)d_out;

    const int M = BB * SS;                        // 4096
    u16* xb  = (u16*)d_ws;                        // M*E
    u16* Wqb = xb  + (size_t)M * EE;              // E*E   } contiguous ->
    u16* Wkb = Wqb + (size_t)EE * EE;             // KVN*E }  single 3072-row
    u16* Wvb = Wkb + (size_t)KVN * EE;            // KVN*E }  B matrix
    u16* Wob = Wvb + (size_t)KVN * EE;            // E*E
    u16* Qg  = Wob + (size_t)EE * EE;             // M*E (pre-scaled by QSCALE)
    u16* Kg  = Qg  + (size_t)M * EE;              // M*KVN
    u16* VtG = Kg  + (size_t)M * KVN;             // M*KVN (transposed)
    u16* ctx = VtG + (size_t)M * KVN;             // M*E

    dim3 blk(256);
    cast_all<<<dim3(NB_X + NB_QO + 2 * NB_KV + NB_QO), blk, 0, stream>>>(
        x, Wq, Wk, Wv, Wo, xb, Wqb, Wkb, Wvb, Wob);

    // fused QKV projection: B = [Wq;Wk;Wv] (3072 x 2048), 256x256 tiles
    gemm_8ph<5><<<dim3(3072 / 256, M / 256), dim3(512), 0, stream>>>(
        xb, Wqb, Qg, Kg, VtG, M, 3072, EE);
    attn_mfma<<<dim3(512), dim3(512), 0, stream>>>(Qg, Kg, VtG, ctx);
    // output projection: 256x256 tiles (grid 8x16 = 128 blocks)
    gemm_8ph<0><<<dim3(EE / 256, M / 256), dim3(512), 0, stream>>>(
        ctx, Wob, out, nullptr, nullptr, M, EE, EE);
}

// Round 6
// 315.627 us; speedup vs baseline: 1.0859x; 1.0041x over previous
//
#include <hip/hip_runtime.h>
#include <math.h>

#define BB 2
#define SS 2048
#define EE 2048
#define HH 16
#define KVHH 4
#define DD 128
#define GG (HH / KVHH)
#define KVN (KVHH * DD)   // 512
#define SCALE 0.08838834764831843f
// SCALE * log2(e): scores land in log2 domain -> exp2f softmax
#define QSCALE (0.08838834764831843f * 1.4426950408889634f)

typedef __attribute__((ext_vector_type(8))) short bf16x8;
typedef __attribute__((ext_vector_type(4))) float f32x4;
typedef unsigned short u16;
typedef unsigned int u32;

__device__ __forceinline__ u16 f2bf(float f) {
    union { float f; u32 u; } x; x.f = f;
    u32 r = x.u + 0x7fff + ((x.u >> 16) & 1);   // RNE
    return (u16)(r >> 16);
}
// HW packed f32->bf16 (RNE), 1 instr for 2 values: lo=bf16(a), hi=bf16(b)
__device__ __forceinline__ u32 cvtpk_bf16(float a, float b) {
    u32 r;
    asm("v_cvt_pk_bf16_f32 %0, %1, %2" : "=v"(r) : "v"(a), "v"(b));
    return r;
}

__device__ __forceinline__ void gload_lds16(const void* g, void* l) {
    __builtin_amdgcn_global_load_lds(
        (const __attribute__((address_space(1))) u32*)g,
        (__attribute__((address_space(3))) u32*)l, 16, 0, 0);
}

// raw workgroup barrier: NO implicit vmcnt/lgkmcnt drain (unlike __syncthreads).
#define RBAR asm volatile("s_barrier" ::: "memory")

// ---------------------------------------------------------------------------
// Fused fp32->bf16 cast of all 5 tensors. Block-granular segments, 1024 el/blk.
// ---------------------------------------------------------------------------
#define NB_X  8192      // B*S*E / 1024
#define NB_QO 4096      // E*E / 1024
#define NB_KV 1024      // KVN*E / 1024
__global__ __launch_bounds__(256) void cast_all(const float* __restrict__ x,
                                                const float* __restrict__ wq,
                                                const float* __restrict__ wk,
                                                const float* __restrict__ wv,
                                                const float* __restrict__ wo,
                                                u16* __restrict__ xb, u16* __restrict__ wqb,
                                                u16* __restrict__ wkb, u16* __restrict__ wvb,
                                                u16* __restrict__ wob) {
    int bid = blockIdx.x;
    const float* src; u16* dst; int off;
    if (bid < NB_X)                       { src = x;  dst = xb;  off = bid * 1024; }
    else if (bid < NB_X + NB_QO)          { src = wq; dst = wqb; off = (bid - NB_X) * 1024; }
    else if (bid < NB_X + NB_QO + NB_KV)  { src = wk; dst = wkb; off = (bid - NB_X - NB_QO) * 1024; }
    else if (bid < NB_X + NB_QO + 2*NB_KV){ src = wv; dst = wvb; off = (bid - NB_X - NB_QO - NB_KV) * 1024; }
    else                                  { src = wo; dst = wob; off = (bid - NB_X - NB_QO - 2*NB_KV) * 1024; }
    int i = off + threadIdx.x * 4;
    float4 v = *(const float4*)&src[i];
    ushort4 o;
    o.x = f2bf(v.x); o.y = f2bf(v.y); o.z = f2bf(v.z); o.w = f2bf(v.w);
    *(ushort4*)&dst[i] = o;
}

// ---------------------------------------------------------------------------
// m97-structure MFMA GEMM (PROVEN: 83 us MODE5 / ~55 us MODE0 in round 3).
// C[M,N] = A[M,K] @ B[N,K]^T, bf16 in, fp32 acc.
// MODE 0: fp32 row-major C
// MODE 5: fused QKV epilogue (B = [Wq;Wk;Wv] concat, N=3072):
//   n<2048      -> Qg bf16 [M][2048], scaled by QSCALE
//   2048..2559  -> Kg bf16 [M][512]
//   2560..3071  -> Vt bf16 [(b*KVN + d)][S]
// ---------------------------------------------------------------------------
template <int MODE>
__global__ __launch_bounds__(256) void gemm_mfma(const u16* __restrict__ A,
                                                 const u16* __restrict__ B,
                                                 void* __restrict__ Cv,
                                                 void* __restrict__ Cv2,
                                                 void* __restrict__ Cv3,
                                                 int M, int N, int K) {
    __shared__ __align__(16) u16 As[128 * 32];
    __shared__ __align__(16) u16 Bs[128 * 32];
    const int tid  = threadIdx.x;
    const int w    = tid >> 6;
    const int lane = tid & 63;
    const int l16  = lane & 15;
    const int quad = lane >> 4;
    const int wm = (w >> 1) * 64;
    const int wn = (w & 1) * 64;
    const int m0 = blockIdx.y * 128;
    const int n0 = blockIdx.x * 128;

    const int r0 = tid >> 2,           ko0 = (tid & 3) * 8;
    const int r1 = (256 + tid) >> 2,   ko1 = (tid & 3) * 8;
    u16* ldsA0 = &As[(size_t)(w * 64) * 8];
    u16* ldsA1 = &As[(size_t)(256 + w * 64) * 8];
    u16* ldsB0 = &Bs[(size_t)(w * 64) * 8];
    u16* ldsB1 = &Bs[(size_t)(256 + w * 64) * 8];

    f32x4 acc[4][4];
#pragma unroll
    for (int i = 0; i < 4; ++i)
#pragma unroll
        for (int j = 0; j < 4; ++j) acc[i][j] = (f32x4){0.f, 0.f, 0.f, 0.f};

    for (int k0 = 0; k0 < K; k0 += 32) {
        __syncthreads();
        gload_lds16(A + (size_t)(m0 + r0) * K + k0 + ko0, ldsA0);
        gload_lds16(A + (size_t)(m0 + r1) * K + k0 + ko1, ldsA1);
        gload_lds16(B + (size_t)(n0 + r0) * K + k0 + ko0, ldsB0);
        gload_lds16(B + (size_t)(n0 + r1) * K + k0 + ko1, ldsB1);
        __syncthreads();

        bf16x8 af[4], bfr[4];
#pragma unroll
        for (int i = 0; i < 4; ++i)
            af[i] = *(const bf16x8*)&As[(wm + i * 16 + l16) * 32 + quad * 8];
#pragma unroll
        for (int j = 0; j < 4; ++j)
            bfr[j] = *(const bf16x8*)&Bs[(wn + j * 16 + l16) * 32 + quad * 8];
#pragma unroll
        for (int i = 0; i < 4; ++i)
#pragma unroll
            for (int j = 0; j < 4; ++j)
                acc[i][j] = __builtin_amdgcn_mfma_f32_16x16x32_bf16(af[i], bfr[j], acc[i][j], 0, 0, 0);
    }

    if (MODE == 0) {
        float* C = (float*)Cv;
#pragma unroll
        for (int i = 0; i < 4; ++i)
#pragma unroll
            for (int j = 0; j < 4; ++j)
#pragma unroll
                for (int reg = 0; reg < 4; ++reg)
                    C[(size_t)(m0 + wm + i * 16 + quad * 4 + reg) * N + n0 + wn + j * 16 + l16] =
                        acc[i][j][reg];
    } else {   // MODE 5
        if (n0 < 2048) {
            u16* C = (u16*)Cv;   // Qg [M][2048], QSCALE folded in
#pragma unroll
            for (int i = 0; i < 4; ++i)
#pragma unroll
                for (int j = 0; j < 4; ++j)
#pragma unroll
                    for (int reg = 0; reg < 4; ++reg)
                        C[(size_t)(m0 + wm + i * 16 + quad * 4 + reg) * 2048 + n0 + wn + j * 16 + l16] =
                            f2bf(acc[i][j][reg] * QSCALE);
        } else if (n0 < 2560) {
            u16* C = (u16*)Cv2;  // Kg [M][512]
            const int nb = n0 - 2048;
#pragma unroll
            for (int i = 0; i < 4; ++i)
#pragma unroll
                for (int j = 0; j < 4; ++j)
#pragma unroll
                    for (int reg = 0; reg < 4; ++reg)
                        C[(size_t)(m0 + wm + i * 16 + quad * 4 + reg) * KVN + nb + wn + j * 16 + l16] =
                            f2bf(acc[i][j][reg]);
        } else {
            u16* C2 = (u16*)Cv3;  // Vt [(b*KVN + d)][S]
            const int db = n0 - 2560;
#pragma unroll
            for (int i = 0; i < 4; ++i) {
                const int m = m0 + wm + i * 16 + quad * 4;
                const int bb = m >> 11;
                const int s  = m & (SS - 1);
#pragma unroll
                for (int j = 0; j < 4; ++j) {
                    const int d = db + wn + j * 16 + l16;
                    ushort4 p;
                    p.x = f2bf(acc[i][j][0]); p.y = f2bf(acc[i][j][1]);
                    p.z = f2bf(acc[i][j][2]); p.w = f2bf(acc[i][j][3]);
                    *(ushort4*)&C2[((size_t)(bb * KVN + d)) * SS + s] = p;
                }
            }
        }
    }
}

// ---------------------------------------------------------------------------
// Flash-style causal GQA attention, bf16 MFMA, Q-tile 128 rows.
// IN-BLOCK SPLIT-K (2 wave-groups x 4 waves, equal NT per group) + T4
// COUNTED-VMCNT PIPELINE: the round-5 profile showed 2 full vmcnt(0) drains
// per tile (__syncthreads B1/B2) = ~10K cyc/tile stall. Now: raw s_barrier
// + counted waits; DMA never drains in steady state.
//   per-tile ledger (per-thread: stageK=4 loads, stageV=4):
//     entry: {K(t):4 oldest, V(t):4} -> vmcnt(4) confirms K(t); RBAR
//     stage K(t+1) into buf^1 (slot idle for 2 barriers)
//     QK + softmax + P-write (P read only by own wave; lgkm in-order)
//     vmcnt(4) confirms V(t) (last iter: vmcnt(0)); RBAR
//     PV; RBAR (all reads retired via MFMA lgkm waits); stage V(t+1)
//   3 barriers/tile, uniform across groups (equal NT). Qa confirmed once
//   via vmcnt(8) after prologue stages.
// ---------------------------------------------------------------------------
__global__ __launch_bounds__(512, 2) void attn_mfma(const u16* __restrict__ Qg,
                                                    const u16* __restrict__ Kg,
                                                    const u16* __restrict__ VtG,
                                                    u16* __restrict__ ctx) {
    __shared__ __align__(16) u16 Ks[2][2][64 * 128];   // [grp][buf] 64 KB
    __shared__ __align__(16) u16 Vt[2][128 * 64];      // [grp] 32 KB
    __shared__ __align__(16) u16 Ps[2][128 * 64];      // [grp] 32 KB

    const int tid  = threadIdx.x;        // 0..511
    const int w    = tid >> 6;           // 0..7
    const int grp  = w >> 2;             // wave-group: 0 = low keys, 1 = high keys
    const int wq   = w & 3;              // q-row wave within group
    const int tg   = tid & 255;          // tid within group
    const int lane = tid & 63;
    const int l16  = lane & 15;
    const int quad = lane >> 4;
    const int sw   = l16 & 7;            // swizzle key for all fragment rows

    // task map: blocks f and f+256 get qc summing to 15 (small first, then big)
    const int f    = blockIdx.x;
    const int half = f >> 8;
    const int u    = f & 255;
    const int h    = u & 15;
    const int w2   = u >> 4;
    const int b    = w2 & 1;
    const int j    = w2 >> 1;                  // 0..7
    const int qc   = half ? (15 - j) : j;      // 0..15
    const int kvh  = h / GG;
    const int q0   = qc * 128;
    const int NT   = qc + 1;                   // k-tiles per group (equal!)

    const size_t kgbase = (size_t)(b * SS) * KVN + kvh * DD;
    const size_t vgbase = (size_t)(b * KVN + kvh * DD) * SS;

    const int myq[2] = { q0 + wq * 16 + l16, q0 + 64 + wq * 16 + l16 };

    // ---- Q fragments direct from global (issued FIRST: oldest vmem ops) ----
    bf16x8 Qa[2][4];
#pragma unroll
    for (int mi = 0; mi < 2; ++mi)
#pragma unroll
        for (int kd = 0; kd < 4; ++kd)
            Qa[mi][kd] = *(const bf16x8*)(Qg + (size_t)(b * SS + myq[mi]) * EE
                                          + h * DD + kd * 32 + quad * 8);

    float m_i[2] = {-INFINITY, -INFINITY};
    float l_i[2] = {0.f, 0.f};          // per-lane partials, reduced at the end
    f32x4 acc_o[2][8];
#pragma unroll
    for (int mi = 0; mi < 2; ++mi)
#pragma unroll
        for (int dt = 0; dt < 8; ++dt) acc_o[mi][dt] = (f32x4){0.f, 0.f, 0.f, 0.f};

    // ---- swizzled async stages (per group, 4 waves each; 4 loads/thread) ----
    auto stageK = [&](int gkt, int buf) {
#pragma unroll
        for (int it = 0; it < 4; ++it) {
            int ci = it * 256 + tg;           // chunk slot (16B units), 1024 total
            int r = ci >> 4, pp = ci & 15;
            int c = (pp & 8) | ((pp ^ r) & 7);
            gload_lds16(Kg + kgbase + (size_t)(gkt * 64 + r) * KVN + c * 8,
                        &Ks[grp][buf][(size_t)(it * 256 + (tg & 192)) * 8]);
        }
    };
    auto stageV = [&](int gkt) {
#pragma unroll
        for (int it = 0; it < 4; ++it) {
            int ci = it * 256 + tg;
            int r = ci >> 3, pp = ci & 7;
            int c = (pp ^ r) & 7;
            gload_lds16(VtG + vgbase + (size_t)r * SS + gkt * 64 + c * 8,
                        &Vt[grp][(size_t)(it * 256 + (tg & 192)) * 8]);
        }
    };

    // ---- prologue: stage K(0), V(0); confirm Qa (leave 8 DMA in flight) ----
    stageK(grp * NT, 0);
    stageV(grp * NT);
    asm volatile("s_waitcnt vmcnt(8)" ::: "memory");
    int buf = 0;

    for (int kt = 0; kt < NT; ++kt) {
        const int gkt = grp * NT + kt;        // global 64-key tile index
        const int gk0 = gkt * 64;             // first key of this tile
        const bool hasNext = (kt + 1 < NT);   // uniform across ALL waves

        // entry ledger: {K(t):4 oldest, V(t):4}
        asm volatile("s_waitcnt vmcnt(4)" ::: "memory");   // K(t) landed (own wave)
        RBAR;                                              // ... and all waves'

        // prefetch next K into the idle buffer (free for 2 barriers already)
        if (hasNext) stageK(gkt + 1, buf ^ 1);   // ledger: {V(t):4, K(t+1):4}

        // per-mi status (wave-uniform): fully-masked / diagonal
        bool skip[2], diag[2];
#pragma unroll
        for (int mi = 0; mi < 2; ++mi) {
            const int lo = q0 + mi * 64;
            skip[mi] = (gk0 > lo + 63);
            diag[mi] = (!skip[mi]) && (gk0 + 63 > lo);
        }

        const u16* kb_base = Ks[grp][buf];

        // ---- S^T = K Q^T : lane q=l16, k = gk0 + kkt*16 + quad*4 + reg ----
        f32x4 sc[2][4];
#pragma unroll
        for (int mi = 0; mi < 2; ++mi)
#pragma unroll
            for (int kkt = 0; kkt < 4; ++kkt) sc[mi][kkt] = (f32x4){0.f, 0.f, 0.f, 0.f};
        __builtin_amdgcn_s_setprio(1);
#pragma unroll
        for (int kkt = 0; kkt < 4; ++kkt) {
            const int R = kkt * 16 + l16;
            bf16x8 kb[4];
#pragma unroll
            for (int kd = 0; kd < 4; ++kd) {
                int c = kd * 4 + quad;
                int pp = (c & 8) | ((c ^ sw) & 7);
                kb[kd] = *(const bf16x8*)&kb_base[(R * 16 + pp) * 8];
            }
            if (!skip[1])
#pragma unroll
                for (int kd = 0; kd < 4; ++kd)
                    sc[1][kkt] = __builtin_amdgcn_mfma_f32_16x16x32_bf16(kb[kd], Qa[1][kd], sc[1][kkt], 0, 0, 0);
            if (!skip[0])
#pragma unroll
                for (int kd = 0; kd < 4; ++kd)
                    sc[0][kkt] = __builtin_amdgcn_mfma_f32_16x16x32_bf16(kb[kd], Qa[0][kd], sc[0][kkt], 0, 0, 0);
        }
        __builtin_amdgcn_s_setprio(0);

        // ---- per-lane online softmax (log2 domain), vote-gated rescale ----
#pragma unroll
        for (int mi = 0; mi < 2; ++mi) {
            if (skip[mi]) continue;
            if (diag[mi]) {
                const int kb0 = gk0 + quad * 4;
#pragma unroll
                for (int kkt = 0; kkt < 4; ++kkt)
#pragma unroll
                    for (int reg = 0; reg < 4; ++reg)
                        if (kb0 + kkt * 16 + reg > myq[mi]) sc[mi][kkt][reg] = -INFINITY;
            }
            float rowmax = -INFINITY;
#pragma unroll
            for (int kkt = 0; kkt < 4; ++kkt)
                rowmax = fmaxf(rowmax,
                               fmaxf(fmaxf(sc[mi][kkt][0], sc[mi][kkt][1]),
                                     fmaxf(sc[mi][kkt][2], sc[mi][kkt][3])));

            if (__any(rowmax > m_i[mi] + 8.0f)) {   // wave-uniform, rare after warmup
                float gmax = fmaxf(rowmax, __shfl_xor(rowmax, 16, 64));
                gmax = fmaxf(gmax, __shfl_xor(gmax, 32, 64));
                float mnew = fmaxf(m_i[mi], gmax);
                float al = exp2f(m_i[mi] - mnew);
                m_i[mi] = mnew;
                l_i[mi] *= al;
#pragma unroll
                for (int dt = 0; dt < 8; ++dt)
#pragma unroll
                    for (int reg = 0; reg < 4; ++reg)
                        acc_o[mi][dt][reg] *= al;
            }

            float rsum = 0.f;
#pragma unroll
            for (int kkt = 0; kkt < 4; ++kkt)
#pragma unroll
                for (int reg = 0; reg < 4; ++reg) {
                    float p = exp2f(sc[mi][kkt][reg] - m_i[mi]);   // bounded by 2^8
                    sc[mi][kkt][reg] = p;
                    rsum += p;
                }
            l_i[mi] += rsum;

            // swizzled packed P^T write via HW cvt_pk (read only by own wave)
            const int prow = mi * 64 + wq * 16 + l16;
#pragma unroll
            for (int kkt = 0; kkt < 4; ++kkt) {
                int ch = (kkt * 2 + (quad >> 1)) ^ sw;
                uint2 pk;
                pk.x = cvtpk_bf16(sc[mi][kkt][0], sc[mi][kkt][1]);
                pk.y = cvtpk_bf16(sc[mi][kkt][2], sc[mi][kkt][3]);
                *(uint2*)&Ps[grp][(prow * 8 + ch) * 8 + (quad & 1) * 4] = pk;
            }
        }

        // confirm V(t): oldest 4 of {V(t):4, K(t+1):4}; last iter drain to 0
        if (hasNext) { asm volatile("s_waitcnt vmcnt(4)" ::: "memory"); }
        else         { asm volatile("s_waitcnt vmcnt(0)" ::: "memory"); }
        RBAR;                                  // V(t) visible to all waves

        // ---- O^T += V^T P^T ----
        const u16* vb_base = Vt[grp];
        __builtin_amdgcn_s_setprio(1);
#pragma unroll
        for (int ks = 0; ks < 2; ++ks) {
            const int pc = (ks * 4 + quad) ^ sw;
            bf16x8 pb1, pb0;
            if (!skip[1]) pb1 = *(const bf16x8*)&Ps[grp][((64 + wq * 16 + l16) * 8 + pc) * 8];
            if (!skip[0]) pb0 = *(const bf16x8*)&Ps[grp][((wq * 16 + l16) * 8 + pc) * 8];
#pragma unroll
            for (int dt = 0; dt < 8; ++dt) {
                bf16x8 va = *(const bf16x8*)&vb_base[((dt * 16 + l16) * 8 + pc) * 8];
                if (!skip[1])
                    acc_o[1][dt] = __builtin_amdgcn_mfma_f32_16x16x32_bf16(va, pb1, acc_o[1][dt], 0, 0, 0);
                if (!skip[0])
                    acc_o[0][dt] = __builtin_amdgcn_mfma_f32_16x16x32_bf16(va, pb0, acc_o[0][dt], 0, 0, 0);
            }
        }
        __builtin_amdgcn_s_setprio(0);

        RBAR;                                  // all waves' V reads retired
        if (hasNext) stageV(gkt + 1);          // ledger: {K(t+1):4, V(t+1):4}
        buf ^= 1;
    }

    // ---- in-block flash merge of the two key-halves ----
    __syncthreads();                          // full drain OK here (once)
    float* dumpO = (float*)&Ks[0][0][0];      // 4 waves * 64 lanes * 64 f32 = 64 KB
    float* dumpML = (float*)&Ps[1][0];        // 4 waves * 64 lanes * 4 f32 = 4 KB
    if (grp == 1) {
        const int base = (wq * 64 + lane) * 64;
#pragma unroll
        for (int mi = 0; mi < 2; ++mi)
#pragma unroll
            for (int dt = 0; dt < 8; ++dt)
                *(f32x4*)&dumpO[base + mi * 32 + dt * 4] = acc_o[mi][dt];
        const int mb = (wq * 64 + lane) * 4;
        dumpML[mb + 0] = m_i[0];
        dumpML[mb + 1] = m_i[1];
        dumpML[mb + 2] = l_i[0];
        dumpML[mb + 3] = l_i[1];
    }
    __syncthreads();                          // dump visible
    if (grp == 0) {
        const int base = (wq * 64 + lane) * 64;
        const int mb = (wq * 64 + lane) * 4;
#pragma unroll
        for (int mi = 0; mi < 2; ++mi) {
            const float m1 = dumpML[mb + mi];
            const float l1 = dumpML[mb + 2 + mi];
            const float ms = fmaxf(m_i[mi], m1);
            const float a0 = exp2f(m_i[mi] - ms);   // 0 if m_i = -inf
            const float a1 = exp2f(m1 - ms);        // 0 if m1  = -inf
            float lt = l_i[mi] * a0 + l1 * a1;
            lt += __shfl_xor(lt, 16, 64);
            lt += __shfl_xor(lt, 32, 64);
            const float linv = 1.f / lt;
            u16* dst = ctx + (size_t)(b * SS + myq[mi]) * EE + h * DD;
#pragma unroll
            for (int dt = 0; dt < 8; ++dt) {
                f32x4 o1 = *(const f32x4*)&dumpO[base + mi * 32 + dt * 4];
                uint2 o;
                o.x = cvtpk_bf16((acc_o[mi][dt][0] * a0 + o1[0] * a1) * linv,
                                 (acc_o[mi][dt][1] * a0 + o1[1] * a1) * linv);
                o.y = cvtpk_bf16((acc_o[mi][dt][2] * a0 + o1[2] * a1) * linv,
                                 (acc_o[mi][dt][3] * a0 + o1[3] * a1) * linv);
                *(uint2*)&dst[dt * 16 + quad * 4] = o;
            }
        }
    }
}

// ---------------------------------------------------------------------------
extern "C" void kernel_launch(void* const* d_in, const int* in_sizes, int n_in,
                              void* d_out, int out_size, void* d_ws, size_t ws_size,
                              hipStream_t stream) {
    const float* x  = (const float*)d_in[0];
    const float* Wq = (const float*)d_in[1];
    const float* Wk = (const float*)d_in[2];
    const float* Wv = (const float*)d_in[3];
    const float* Wo = (const float*)d_in[4];
    float* out = (float*)d_out;

    const int M = BB * SS;                        // 4096
    u16* xb  = (u16*)d_ws;                        // M*E
    u16* Wqb = xb  + (size_t)M * EE;              // E*E   } contiguous ->
    u16* Wkb = Wqb + (size_t)EE * EE;             // KVN*E }  single 3072-row
    u16* Wvb = Wkb + (size_t)KVN * EE;            // KVN*E }  B matrix
    u16* Wob = Wvb + (size_t)KVN * EE;            // E*E
    u16* Qg  = Wob + (size_t)EE * EE;             // M*E (pre-scaled by QSCALE)
    u16* Kg  = Qg  + (size_t)M * EE;              // M*KVN
    u16* VtG = Kg  + (size_t)M * KVN;             // M*KVN (transposed)
    u16* ctx = VtG + (size_t)M * KVN;             // M*E

    dim3 blk(256);
    cast_all<<<dim3(NB_X + NB_QO + 2 * NB_KV + NB_QO), blk, 0, stream>>>(
        x, Wq, Wk, Wv, Wo, xb, Wqb, Wkb, Wvb, Wob);

    // fused QKV projection: B = [Wq;Wk;Wv] (3072 x 2048), m97 128-tiles
    gemm_mfma<5><<<dim3(3072 / 128, M / 128), blk, 0, stream>>>(
        xb, Wqb, Qg, Kg, VtG, M, 3072, EE);
    attn_mfma<<<dim3(512), dim3(512), 0, stream>>>(Qg, Kg, VtG, ctx);
    gemm_mfma<0><<<dim3(EE / 128, M / 128), blk, 0, stream>>>(
        ctx, Wob, out, nullptr, nullptr, M, EE, EE);
}